// Round 5
// baseline (120.498 us; speedup 1.0000x reference)
//
#include <hip/hip_runtime.h>

typedef unsigned short u16;
typedef __bf16 bf16x8 __attribute__((ext_vector_type(8)));
typedef float f32x4 __attribute__((ext_vector_type(4)));

#define WEMD 400
#define RANK 396
#define NA   16384     // SEQ*BATCH
#define KP   416       // padded wemd (400->416) for gemm_h K
#define K2   448       // padded rank (396->448) for gemm_big K (7 tiles of 64)
#define BSTR 896       // byte stride of H and G rows (448*2)
#define NBC  2500
#define NBCP 2560

// ---- ws layout (bytes) ----
#define OFF_WBF  0u                 // u16 [16416][416]
#define OFF_UBT  13658112u          // u16 [512][416]
#define OFF_TBT  14084096u          // u16 [512][416]
#define OFF_G    14689280u          // u16 [2560][448]
#define OFF_H    16983040u          // u16 [16384][448]   total ~31.7 MB

__device__ __forceinline__ u16 f2bf(float f) {
  union { float f; unsigned u; } v; v.f = f;
  unsigned u = v.u;
  return (u16)((u + 0x7FFFu + ((u >> 16) & 1u)) >> 16);  // RNE
}

typedef __attribute__((address_space(3))) unsigned char lds_byte;
typedef __attribute__((address_space(1))) const unsigned char glob_byte;

__device__ __forceinline__ void gload16(const void* g, void* l) {
  __builtin_amdgcn_global_load_lds((glob_byte*)g, (lds_byte*)l, 16, 0, 0);
}

#define FENCE() asm volatile("" ::: "memory")
#define BARRIER() do { FENCE(); __builtin_amdgcn_s_barrier(); FENCE(); } while (0)
#define VMCNT0() asm volatile("s_waitcnt vmcnt(0)" ::: "memory")

// ---------- fused prep: Wbf + Ubt/Tbt + G in one grid-stride kernel ----------
__global__ __launch_bounds__(256) void prep_all(
    const float* __restrict__ word, const float* __restrict__ first,
    const float* __restrict__ U, const float* __restrict__ T,
    const float* __restrict__ tag, const float* __restrict__ V,
    const float* __restrict__ W,
    u16* __restrict__ Wbf, u16* __restrict__ Ubt, u16* __restrict__ Tbt,
    u16* __restrict__ G) {
  const int R0 = 16416 * 104;          // Wbf as float4 items (416/4 = 104 per row)
  const int R1 = 416 << 9;             // U/T transpose: k = j>>9 (0..415), n = j&511
  const int R2 = NBCP * K2;            // G items
  const int total = R0 + R1 + R2;
  for (int i = blockIdx.x * 256 + threadIdx.x; i < total; i += gridDim.x * 256) {
    if (i < R0) {
      int r = i / 104, c4 = i - r * 104;
      ushort4 o = {0, 0, 0, 0};
      if (c4 < 100) {
        const float* src = (r < 32) ? (first + c4 * 4)
                                    : (word + (size_t)(r - 32) * WEMD + c4 * 4);
        float4 v = *(const float4*)src;
        o.x = f2bf(v.x); o.y = f2bf(v.y); o.z = f2bf(v.z); o.w = f2bf(v.w);
      }
      *(ushort4*)(Wbf + (size_t)r * KP + c4 * 4) = o;
    } else if (i < R0 + R1) {
      int j = i - R0;
      int n = j & 511, k = j >> 9;
      u16 uo = 0, to = 0;
      if (n < RANK && k < WEMD) {
        uo = f2bf(U[(size_t)k * RANK + n]);
        to = f2bf(T[(size_t)k * RANK + n]);
      }
      Ubt[(size_t)n * KP + k] = uo;
      Tbt[(size_t)n * KP + k] = to;
    } else {
      int j = i - R0 - R1;
      int bc = j / K2, k = j - bc * K2;
      u16 g = 0;
      if (bc < NBC && k < RANK) {
        int b = bc / 50, c = bc - b * 50;
        float a2 = 0.f, a3 = 0.f;
        #pragma unroll
        for (int e = 0; e < 20; ++e) {
          a2 += tag[b * 20 + e] * V[e * RANK + k];
          a3 += tag[c * 20 + e] * W[e * RANK + k];
        }
        g = f2bf(a2 * a3);
      }
      G[(size_t)bc * K2 + k] = g;
    }
  }
}

// ---------- H = (word@U) * (neighbor@T), bf16 out, stride 448 ----------
__global__ __launch_bounds__(256) void gemm_h(const u16* __restrict__ Wbf,
                                              const u16* __restrict__ Ubt,
                                              const u16* __restrict__ Tbt,
                                              u16* __restrict__ H) {
  __shared__ u16 As0[128 * 32], As1[128 * 32], Bu[128 * 32], Bt[128 * 32];
  const int tid = threadIdx.x;
  const int l = tid & 63, w = tid >> 6;
  const int wm = w >> 1, wn = w & 1;
  const int tm = (blockIdx.x >> 2) * 128, tn = (blockIdx.x & 3) * 128;

  f32x4 acc0[4][4] = {}, acc1[4][4] = {};

  const int srow = tid >> 2;
  const int scolb = (tid & 3) * 16;
  const char* gA0 = (const char*)Wbf + (size_t)(tm + 32 + srow) * 832 + scolb;
  const char* gA1 = (const char*)Wbf + (size_t)(tm + srow) * 832 + scolb;
  const char* gU  = (const char*)Ubt + (size_t)(tn + srow) * 832 + scolb;
  const char* gT  = (const char*)Tbt + (size_t)(tn + srow) * 832 + scolb;
  char* lA0 = (char*)As0 + tid * 16;
  char* lA1 = (char*)As1 + tid * 16;
  char* lU  = (char*)Bu  + tid * 16;
  char* lT  = (char*)Bt  + tid * 16;

  const int fo_a = (wm * 64 + (l & 15)) * 32 + (l >> 4) * 8;
  const int fo_b = (wn * 64 + (l & 15)) * 32 + (l >> 4) * 8;

  for (int kt = 0; kt < 13; ++kt) {
    const int kb = kt * 64;
    gload16(gA0 + kb, lA0); gload16(gA0 + kb + (size_t)64 * 832, lA0 + 4096);
    gload16(gA1 + kb, lA1); gload16(gA1 + kb + (size_t)64 * 832, lA1 + 4096);
    gload16(gU  + kb, lU ); gload16(gU  + kb + (size_t)64 * 832, lU  + 4096);
    gload16(gT  + kb, lT ); gload16(gT  + kb + (size_t)64 * 832, lT  + 4096);
    __syncthreads();
    bf16x8 a0[4], a1[4], bu[4], bt[4];
    #pragma unroll
    for (int i = 0; i < 4; ++i) {
      a0[i] = *(const bf16x8*)(As0 + fo_a + i * 16 * 32);
      a1[i] = *(const bf16x8*)(As1 + fo_a + i * 16 * 32);
      bu[i] = *(const bf16x8*)(Bu  + fo_b + i * 16 * 32);
      bt[i] = *(const bf16x8*)(Bt  + fo_b + i * 16 * 32);
    }
    #pragma unroll
    for (int i = 0; i < 4; ++i)
      #pragma unroll
      for (int j = 0; j < 4; ++j) {
        acc0[i][j] = __builtin_amdgcn_mfma_f32_16x16x32_bf16(a0[i], bu[j], acc0[i][j], 0, 0, 0);
        acc1[i][j] = __builtin_amdgcn_mfma_f32_16x16x32_bf16(a1[i], bt[j], acc1[i][j], 0, 0, 0);
      }
    __syncthreads();
  }

  const int r4 = (l >> 4) * 4, cc = l & 15;
  #pragma unroll
  for (int i = 0; i < 4; ++i)
    #pragma unroll
    for (int j = 0; j < 4; ++j) {
      const int col = tn + wn * 64 + j * 16 + cc;
      if (col < K2) {
        #pragma unroll
        for (int r = 0; r < 4; ++r) {
          const int rowg = tm + wm * 64 + i * 16 + r4 + r;
          H[(size_t)rowg * K2 + col] = f2bf(acc0[i][j][r] * acc1[i][j][r]);
        }
      }
    }
}

// ---------- out[16384,2500] = H[.,448] @ G^T ----------
// 128x128 tile, BK=64, 256 thr (4 waves 2x2), NOW double-buffered (T3-min
// 2-phase): issue next tile's STAGE into buf^1 BEFORE computing on buf, then
// one vmcnt(0)+barrier per iter. L2 latency hides under 16 ds_read + 32 MFMA.
// LDS 64 KiB -> 2 blocks/CU.
// Swizzle (validated R2-R4): physical = logical ^ ((row&7)<<4) on both sides.
__global__ __launch_bounds__(256, 2) void gemm_big2(const u16* __restrict__ H,
                                                    const u16* __restrict__ G,
                                                    float* __restrict__ out) {
  __shared__ u16 lds[4 * 8192];   // 64 KiB: buf0{A,B} + buf1{A,B}
  char* ldsb = (char*)lds;
  const int tid = threadIdx.x;
  const int lane = tid & 63, wid = tid >> 6;
  const int wm = wid >> 1, wn = wid & 1;

  int bs = (int)blockIdx.x;
  bs = (bs & 7) * 320 + (bs >> 3);              // XCD swizzle, 2560 % 8 == 0
  const int tm = (bs / 20) * 128, tn = (bs % 20) * 128;

  const char* gH = (const char*)H + (size_t)tm * BSTR;
  const char* gG = (const char*)G + (size_t)tn * BSTR;

  // stage addressing: 4 x 16B per thread per operand tile
  int sP[4], sR[4], sC[4];
  #pragma unroll
  for (int q = 0; q < 4; ++q) {
    int P = tid * 16 + q * 4096;
    int L = P ^ (((P >> 7) & 7) << 4);
    sP[q] = P; sR[q] = L >> 7; sC[q] = L & 127;
  }
  const int arow = (lane & 15) * 128;
  const int sw = (lane & 7) << 4;

  f32x4 acc[4][4] = {};

  // prologue: stage tile 0 into buf0
  #pragma unroll
  for (int q = 0; q < 4; ++q) {
    gload16(gH + (size_t)sR[q] * BSTR + sC[q], ldsb + sP[q]);
    gload16(gG + (size_t)sR[q] * BSTR + sC[q], ldsb + 16384 + sP[q]);
  }
  VMCNT0();
  BARRIER();

  for (int kt = 0; kt < 7; ++kt) {
    const int cur = kt & 1;
    char* cbuf = ldsb + cur * 32768;

    if (kt < 6) {                               // issue next tile's loads FIRST
      char* nbuf = ldsb + (cur ^ 1) * 32768;
      const int kb = (kt + 1) * 128;
      #pragma unroll
      for (int q = 0; q < 4; ++q) {
        gload16(gH + (size_t)sR[q] * BSTR + kb + sC[q], nbuf + sP[q]);
        gload16(gG + (size_t)sR[q] * BSTR + kb + sC[q], nbuf + 16384 + sP[q]);
      }
    }

    #pragma unroll
    for (int ks = 0; ks < 2; ++ks) {
      const int csw = (ks * 64 + (lane >> 4) * 16) ^ sw;
      bf16x8 a[4], b[4];
      #pragma unroll
      for (int rf = 0; rf < 4; ++rf)
        a[rf] = *(const bf16x8*)(cbuf + wm * 8192 + rf * 2048 + arow + csw);
      #pragma unroll
      for (int cf = 0; cf < 4; ++cf)
        b[cf] = *(const bf16x8*)(cbuf + 16384 + wn * 8192 + cf * 2048 + arow + csw);
      #pragma unroll
      for (int rf = 0; rf < 4; ++rf)
        #pragma unroll
        for (int cf = 0; cf < 4; ++cf)
          acc[rf][cf] = __builtin_amdgcn_mfma_f32_16x16x32_bf16(a[rf], b[cf], acc[rf][cf], 0, 0, 0);
    }

    if (kt < 6) {
      VMCNT0();                                 // next tile resident
      BARRIER();                                // all waves done with cbuf
    }
  }

  const int r4 = (lane >> 4) * 4, cc = lane & 15;
  const int rbase = tm + wm * 64 + r4;
  const int cbase = tn + wn * 64 + cc;
  #pragma unroll
  for (int rf = 0; rf < 4; ++rf)
    #pragma unroll
    for (int cf = 0; cf < 4; ++cf) {
      const int col = cbase + cf * 16;
      if (col < NBC) {
        #pragma unroll
        for (int rr = 0; rr < 4; ++rr)
          out[(size_t)(rbase + rf * 16 + rr) * NBC + col] = acc[rf][cf][rr];
      }
    }
}

extern "C" void kernel_launch(void* const* d_in, const int* in_sizes, int n_in,
                              void* d_out, int out_size, void* d_ws, size_t ws_size,
                              hipStream_t stream) {
  const float* word  = (const float*)d_in[0];
  const float* tag   = (const float*)d_in[1];
  const float* Tm    = (const float*)d_in[2];
  const float* Um    = (const float*)d_in[3];
  const float* Vm    = (const float*)d_in[4];
  const float* Wm    = (const float*)d_in[5];
  const float* first = (const float*)d_in[6];
  float* out = (float*)d_out;
  char* ws = (char*)d_ws;

  u16*   Wbf = (u16*)(ws + OFF_WBF);
  u16*   Ubt = (u16*)(ws + OFF_UBT);
  u16*   Tbt = (u16*)(ws + OFF_TBT);
  u16*   G   = (u16*)(ws + OFF_G);
  u16*   H   = (u16*)(ws + OFF_H);

  hipLaunchKernelGGL(prep_all, dim3(2048), dim3(256), 0, stream,
                     word, first, Um, Tm, tag, Vm, Wm, Wbf, Ubt, Tbt, G);
  hipLaunchKernelGGL(gemm_h,   dim3(128 * 4), dim3(256), 0, stream, Wbf, Ubt, Tbt, H);
  hipLaunchKernelGGL(gemm_big2, dim3(2560), dim3(256), 0, stream, H, G, out);
}

// Round 6
// 117.921 us; speedup vs baseline: 1.0219x; 1.0219x over previous
//
#include <hip/hip_runtime.h>

typedef unsigned short u16;
typedef __bf16 bf16x8 __attribute__((ext_vector_type(8)));
typedef float f32x4 __attribute__((ext_vector_type(4)));

#define WEMD 400
#define RANK 396
#define NA   16384     // SEQ*BATCH
#define KP   416       // padded wemd (400->416) for gemm_h K
#define K2   448       // padded rank (396->448) for gemm_big K (7 chunks of 64)
#define BSTR 896       // byte stride of H and G rows (448*2)
#define NBC  2500
#define NBCP 2560

// ---- ws layout (bytes) ----
#define OFF_WBF  0u                 // u16 [16416][416]
#define OFF_UBT  13658112u          // u16 [512][416]
#define OFF_TBT  14084096u          // u16 [512][416]
#define OFF_G    14689280u          // u16 [2560][448]
#define OFF_H    16983040u          // u16 [16384][448]   total ~31.7 MB

__device__ __forceinline__ u16 f2bf(float f) {
  union { float f; unsigned u; } v; v.f = f;
  unsigned u = v.u;
  return (u16)((u + 0x7FFFu + ((u >> 16) & 1u)) >> 16);  // RNE
}

typedef __attribute__((address_space(3))) unsigned char lds_byte;
typedef __attribute__((address_space(1))) const unsigned char glob_byte;

__device__ __forceinline__ void gload16(const void* g, void* l) {
  __builtin_amdgcn_global_load_lds((glob_byte*)g, (lds_byte*)l, 16, 0, 0);
}

#define FENCE() asm volatile("" ::: "memory")
#define BARRIER() do { FENCE(); __builtin_amdgcn_s_barrier(); FENCE(); } while (0)
#define VMCNT0()  asm volatile("s_waitcnt vmcnt(0)"  ::: "memory")
#define VMCNT2()  asm volatile("s_waitcnt vmcnt(2)"  ::: "memory")
#define VMCNT34() asm volatile("s_waitcnt vmcnt(34)" ::: "memory")

// ---------- fused prep: Wbf + Ubt/Tbt + G in one grid-stride kernel ----------
__global__ __launch_bounds__(256) void prep_all(
    const float* __restrict__ word, const float* __restrict__ first,
    const float* __restrict__ U, const float* __restrict__ T,
    const float* __restrict__ tag, const float* __restrict__ V,
    const float* __restrict__ W,
    u16* __restrict__ Wbf, u16* __restrict__ Ubt, u16* __restrict__ Tbt,
    u16* __restrict__ G) {
  const int R0 = 16416 * 104;          // Wbf as float4 items (416/4 = 104 per row)
  const int R1 = 416 << 9;             // U/T transpose: k = j>>9 (0..415), n = j&511
  const int R2 = NBCP * K2;            // G items
  const int total = R0 + R1 + R2;
  for (int i = blockIdx.x * 256 + threadIdx.x; i < total; i += gridDim.x * 256) {
    if (i < R0) {
      int r = i / 104, c4 = i - r * 104;
      ushort4 o = {0, 0, 0, 0};
      if (c4 < 100) {
        const float* src = (r < 32) ? (first + c4 * 4)
                                    : (word + (size_t)(r - 32) * WEMD + c4 * 4);
        float4 v = *(const float4*)src;
        o.x = f2bf(v.x); o.y = f2bf(v.y); o.z = f2bf(v.z); o.w = f2bf(v.w);
      }
      *(ushort4*)(Wbf + (size_t)r * KP + c4 * 4) = o;
    } else if (i < R0 + R1) {
      int j = i - R0;
      int n = j & 511, k = j >> 9;
      u16 uo = 0, to = 0;
      if (n < RANK && k < WEMD) {
        uo = f2bf(U[(size_t)k * RANK + n]);
        to = f2bf(T[(size_t)k * RANK + n]);
      }
      Ubt[(size_t)n * KP + k] = uo;
      Tbt[(size_t)n * KP + k] = to;
    } else {
      int j = i - R0 - R1;
      int bc = j / K2, k = j - bc * K2;
      u16 g = 0;
      if (bc < NBC && k < RANK) {
        int b = bc / 50, c = bc - b * 50;
        float a2 = 0.f, a3 = 0.f;
        #pragma unroll
        for (int e = 0; e < 20; ++e) {
          a2 += tag[b * 20 + e] * V[e * RANK + k];
          a3 += tag[c * 20 + e] * W[e * RANK + k];
        }
        g = f2bf(a2 * a3);
      }
      G[(size_t)bc * K2 + k] = g;
    }
  }
}

// ---------- H = (word@U) * (neighbor@T), bf16 out, stride 448 ----------
__global__ __launch_bounds__(256) void gemm_h(const u16* __restrict__ Wbf,
                                              const u16* __restrict__ Ubt,
                                              const u16* __restrict__ Tbt,
                                              u16* __restrict__ H) {
  __shared__ u16 As0[128 * 32], As1[128 * 32], Bu[128 * 32], Bt[128 * 32];
  const int tid = threadIdx.x;
  const int l = tid & 63, w = tid >> 6;
  const int wm = w >> 1, wn = w & 1;
  const int tm = (blockIdx.x >> 2) * 128, tn = (blockIdx.x & 3) * 128;

  f32x4 acc0[4][4] = {}, acc1[4][4] = {};

  const int srow = tid >> 2;
  const int scolb = (tid & 3) * 16;
  const char* gA0 = (const char*)Wbf + (size_t)(tm + 32 + srow) * 832 + scolb;
  const char* gA1 = (const char*)Wbf + (size_t)(tm + srow) * 832 + scolb;
  const char* gU  = (const char*)Ubt + (size_t)(tn + srow) * 832 + scolb;
  const char* gT  = (const char*)Tbt + (size_t)(tn + srow) * 832 + scolb;
  char* lA0 = (char*)As0 + tid * 16;
  char* lA1 = (char*)As1 + tid * 16;
  char* lU  = (char*)Bu  + tid * 16;
  char* lT  = (char*)Bt  + tid * 16;

  const int fo_a = (wm * 64 + (l & 15)) * 32 + (l >> 4) * 8;
  const int fo_b = (wn * 64 + (l & 15)) * 32 + (l >> 4) * 8;

  for (int kt = 0; kt < 13; ++kt) {
    const int kb = kt * 64;
    gload16(gA0 + kb, lA0); gload16(gA0 + kb + (size_t)64 * 832, lA0 + 4096);
    gload16(gA1 + kb, lA1); gload16(gA1 + kb + (size_t)64 * 832, lA1 + 4096);
    gload16(gU  + kb, lU ); gload16(gU  + kb + (size_t)64 * 832, lU  + 4096);
    gload16(gT  + kb, lT ); gload16(gT  + kb + (size_t)64 * 832, lT  + 4096);
    __syncthreads();
    bf16x8 a0[4], a1[4], bu[4], bt[4];
    #pragma unroll
    for (int i = 0; i < 4; ++i) {
      a0[i] = *(const bf16x8*)(As0 + fo_a + i * 16 * 32);
      a1[i] = *(const bf16x8*)(As1 + fo_a + i * 16 * 32);
      bu[i] = *(const bf16x8*)(Bu  + fo_b + i * 16 * 32);
      bt[i] = *(const bf16x8*)(Bt  + fo_b + i * 16 * 32);
    }
    #pragma unroll
    for (int i = 0; i < 4; ++i)
      #pragma unroll
      for (int j = 0; j < 4; ++j) {
        acc0[i][j] = __builtin_amdgcn_mfma_f32_16x16x32_bf16(a0[i], bu[j], acc0[i][j], 0, 0, 0);
        acc1[i][j] = __builtin_amdgcn_mfma_f32_16x16x32_bf16(a1[i], bt[j], acc1[i][j], 0, 0, 0);
      }
    __syncthreads();
  }

  const int r4 = (l >> 4) * 4, cc = l & 15;
  #pragma unroll
  for (int i = 0; i < 4; ++i)
    #pragma unroll
    for (int j = 0; j < 4; ++j) {
      const int col = tn + wn * 64 + j * 16 + cc;
      if (col < K2) {
        #pragma unroll
        for (int r = 0; r < 4; ++r) {
          const int rowg = tm + wm * 64 + i * 16 + r4 + r;
          H[(size_t)rowg * K2 + col] = f2bf(acc0[i][j][r] * acc1[i][j][r]);
        }
      }
    }
}

// ---------- out[16384,2500] = H @ G^T : persistent H-panel kernel ----------
// 256 blocks x 512 thr (8 waves 2Mx4N). Each block: H-panel [128][448] staged
// ONCE into LDS (112 KB, swizzled), then loops 10 N-tiles of G (chunks [128][64B*2]
// double-buffered, 16 KB each). Output stores are fire-and-forget; waits use
// counted vmcnt relying on in-order vmem retirement:
//   per k-iter queue is [pf(j)][pf(j+1)] -> vmcnt(2);
//   at tile-start (nt>0) queue is [pf(2)][stores(32)][pf(2)] -> vmcnt(34).
// Swizzle (validated): physical_col = logical_col ^ ((row&7)<<4), both sides.
#define STAGEG(ntg, ktc, bsel)                                                     \
  do {                                                                             \
    _Pragma("unroll")                                                              \
    for (int q = 0; q < 2; ++q) {                                                  \
      int P = tid * 16 + q * 8192;                                                 \
      int row = P >> 7;                                                            \
      int col = (P & 127) ^ ((row & 7) << 4);                                      \
      gload16(gG + (size_t)((ntg) * 128 + row) * BSTR + (ktc) * 128 + col,         \
              ldsb + 114688 + (bsel) * 16384 + P);                                 \
    }                                                                              \
  } while (0)

__global__ __launch_bounds__(512, 2) void gemm_pers(const u16* __restrict__ H,
                                                    const u16* __restrict__ G,
                                                    float* __restrict__ out) {
  __shared__ u16 lds[73728];     // 112 KB H-panel + 2 x 16 KB G-chunk = 144 KB
  char* ldsb = (char*)lds;
  const int tid = threadIdx.x;
  const int lane = tid & 63, wid = tid >> 6;
  const int wm = wid >> 2, wn = wid & 3;          // 2M x 4N waves

  int bs = (int)blockIdx.x;
  bs = (bs & 7) * 32 + (bs >> 3);                 // XCD swizzle, 256 % 8 == 0
  const int tm = (bs >> 1) * 128;
  const int nt0 = (bs & 1) * 10;

  const char* gH = (const char*)H;
  const char* gG = (const char*)G;

  // ---- stage H-panel [128][896B], swizzled, 14 x 16B per thread ----
  #pragma unroll
  for (int q = 0; q < 14; ++q) {
    int P = tid * 16 + q * 8192;
    int row = P / 896;
    int colp = P - row * 896;
    int col = colp ^ ((row & 7) << 4);
    gload16(gH + (size_t)(tm + row) * BSTR + col, ldsb + P);
  }
  STAGEG(nt0, 0, 0);
  VMCNT0();
  BARRIER();

  const int al = lane & 15;
  const int ah = (lane >> 4) * 16;
  const int sw = (lane & 7) << 4;
  const int r4 = (lane >> 4) * 4;

  f32x4 acc[4][2] = {};
  int buf = 0;

  for (int nt = 0; nt < 10; ++nt) {
    for (int kt = 0; kt < 7; ++kt) {
      const bool last = (nt == 9) && (kt == 6);
      if (!last) {
        int nkt = kt + 1, nnt = nt;
        if (nkt == 7) { nkt = 0; nnt = nt + 1; }
        STAGEG(nt0 + nnt, nkt, buf ^ 1);
      }
      if (last)                { VMCNT0(); }
      else if (kt == 0 && nt)  { VMCNT34(); }   // [pf 2][stores 32][pf 2] in order
      else                     { VMCNT2();  }
      BARRIER();

      #pragma unroll
      for (int ks = 0; ks < 2; ++ks) {
        const int ca = (kt * 128 + ks * 64 + ah) ^ sw;
        const int cb = (ks * 64 + ah) ^ sw;
        bf16x8 a[4], bv[2];
        #pragma unroll
        for (int rf = 0; rf < 4; ++rf)
          a[rf] = *(const bf16x8*)(ldsb + (size_t)(wm * 64 + rf * 16 + al) * BSTR + ca);
        #pragma unroll
        for (int cf = 0; cf < 2; ++cf)
          bv[cf] = *(const bf16x8*)(ldsb + 114688 + buf * 16384 +
                                    (wn * 32 + cf * 16 + al) * 128 + cb);
        #pragma unroll
        for (int rf = 0; rf < 4; ++rf)
          #pragma unroll
          for (int cf = 0; cf < 2; ++cf)
            acc[rf][cf] = __builtin_amdgcn_mfma_f32_16x16x32_bf16(a[rf], bv[cf], acc[rf][cf], 0, 0, 0);
      }
      BARRIER();
      buf ^= 1;

      if (kt == 6) {
        // fire-and-forget epilogue for tile nt (exactly 32 dword stores/thread
        // for nt_g < 19; the guarded tile 19 is last and has no successor wait)
        const int colb = (nt0 + nt) * 128 + wn * 32 + al;
        #pragma unroll
        for (int rf = 0; rf < 4; ++rf)
          #pragma unroll
          for (int cf = 0; cf < 2; ++cf) {
            const int col = colb + cf * 16;
            if (col < NBC) {
              #pragma unroll
              for (int rr = 0; rr < 4; ++rr)
                out[(size_t)(tm + wm * 64 + rf * 16 + r4 + rr) * NBC + col] = acc[rf][cf][rr];
            }
            acc[rf][cf] = f32x4{0.f, 0.f, 0.f, 0.f};
          }
      }
    }
  }
}

extern "C" void kernel_launch(void* const* d_in, const int* in_sizes, int n_in,
                              void* d_out, int out_size, void* d_ws, size_t ws_size,
                              hipStream_t stream) {
  const float* word  = (const float*)d_in[0];
  const float* tag   = (const float*)d_in[1];
  const float* Tm    = (const float*)d_in[2];
  const float* Um    = (const float*)d_in[3];
  const float* Vm    = (const float*)d_in[4];
  const float* Wm    = (const float*)d_in[5];
  const float* first = (const float*)d_in[6];
  float* out = (float*)d_out;
  char* ws = (char*)d_ws;

  u16*   Wbf = (u16*)(ws + OFF_WBF);
  u16*   Ubt = (u16*)(ws + OFF_UBT);
  u16*   Tbt = (u16*)(ws + OFF_TBT);
  u16*   G   = (u16*)(ws + OFF_G);
  u16*   H   = (u16*)(ws + OFF_H);

  hipLaunchKernelGGL(prep_all, dim3(2048), dim3(256), 0, stream,
                     word, first, Um, Tm, tag, Vm, Wm, Wbf, Ubt, Tbt, G);
  hipLaunchKernelGGL(gemm_h,   dim3(128 * 4), dim3(256), 0, stream, Wbf, Ubt, Tbt, H);
  hipLaunchKernelGGL(gemm_pers, dim3(256), dim3(512), 0, stream, H, G, out);
}